// Round 5
// baseline (162.408 us; speedup 1.0000x reference)
//
#include <hip/hip_runtime.h>

typedef __bf16 bf16x8 __attribute__((ext_vector_type(8)));
typedef float f32x4 __attribute__((ext_vector_type(4)));

#define HH 64
#define WW 64
#define HW 4096
#define COUT 256
#define NROWS 12      // staged input rows [rowbase, rowbase+11]
#define XS_OFF 37888  // Xs after Bs (64 px rows x 592 B)
#define SMEM_SZ 65536 // Bs 37888 | Xs 24576 (12 rows x 2 sg x 64 col x 16 B)

// lgkm-only barrier: staging DMA stays in flight across it.
__device__ __forceinline__ void bar_sync() {
    asm volatile("s_waitcnt lgkmcnt(0)" ::: "memory");
    __builtin_amdgcn_s_barrier();
    asm volatile("" ::: "memory");
}
// full barrier: drains this wave's global_load_lds DMA before the barrier.
__device__ __forceinline__ void bar_sync_vm() {
    asm volatile("s_waitcnt vmcnt(0) lgkmcnt(0)" ::: "memory");
    __builtin_amdgcn_s_barrier();
    asm volatile("" ::: "memory");
}

// ---------------------------------------------------------------------------
// Kernel 1 (merged pre-pass, 512 blocks):
//   blocks 0..255   : transpose x -> bf16 stage-major xs[b][h][g16][sg][w][c8]
//   blocks 256..511 : blend circle weights -> bf16 pre-fragmented MFMA A.
// ---------------------------------------------------------------------------
__global__ __launch_bounds__(256) void prep(const float* __restrict__ weight,
                                            const float* __restrict__ x,
                                            __bf16* __restrict__ wp,
                                            __bf16* __restrict__ xs) {
    __shared__ float ws[2304];
    const int tid = threadIdx.x;
    if (blockIdx.x < 256) {
        // ---- x transpose: one block per (b,h) -----------------------------
        const int bh = blockIdx.x;
        const int b = bh >> 6, h = bh & 63;
        const float* xr = x + (size_t)b * 256 * HW + h * 64;
        #pragma unroll
        for (int it = 0; it < 8; ++it) {
            const int u = it * 256 + tid;        // 16B chunk index 0..2047
            const int gsg = u >> 6, w = u & 63;  // c = gsg*8 + c8
            bf16x8 v;
            #pragma unroll
            for (int c8 = 0; c8 < 8; ++c8)
                v[c8] = (__bf16)xr[(size_t)(gsg * 8 + c8) * HW + w];
            *(bf16x8*)&xs[(size_t)bh * 16384 + (size_t)u * 8] = v;
        }
        return;
    }
    // ---- circle-weight blend: one block per output row o ------------------
    const int o = blockIdx.x - 256;
    const float4* src = (const float4*)(weight + (size_t)o * 2304);
    float4* dst = (float4*)ws;
    #pragma unroll
    for (int i = 0; i < 3; ++i) {
        int idx = i * 256 + tid;
        if (idx < 576) dst[idx] = src[idx];
    }
    __syncthreads();
    const float Af = 0.70710678118654752f;
    const float Bf = 1.0f - Af;
    const int tm = o >> 4, rr = o & 15;
    for (int fid = tid; fid < 288; fid += 256) {
        const int cgtap = fid >> 2, q = fid & 3;
        const int cg = cgtap / 9, tap = cgtap - 9 * cg;
        const int c0 = cg * 32 + q * 8;
        bf16x8 v;
        #pragma unroll
        for (int j = 0; j < 8; ++j) {
            const float* w = ws + (c0 + j) * 9;
            float r;
            switch (tap) {
                case 0:  r = Af*(Af*w[0]+Bf*w[1]) + Bf*(Af*w[3]+Bf*w[4]); break;
                case 1:  r = w[1]; break;
                case 2:  r = Af*(Bf*w[1]+Af*w[2]) + Bf*(Bf*w[4]+Af*w[5]); break;
                case 3:  r = w[3]; break;
                case 4:  r = w[4]; break;
                case 5:  r = w[5]; break;
                case 6:  r = Bf*(Af*w[3]+Bf*w[4]) + Af*(Af*w[6]+Bf*w[7]); break;
                case 7:  r = w[7]; break;
                default: r = Bf*(Bf*w[4]+Af*w[5]) + Af*(Bf*w[7]+Af*w[8]); break;
            }
            v[j] = (__bf16)r;
        }
        *(bf16x8*)&wp[(size_t)(((cg * 9 + tap) * 16 + tm) * 64 + q * 16 + rr) << 3] = v;
    }
}

// ---------------------------------------------------------------------------
// Kernel 2: DMA-staged bilinear-sample + implicit GEMM, deep A-prefetch.
// launch_bounds(512, 1): empirical VGPR cap = 256/min_waves_arg for 512-thr
// blocks (R1: arg=4 -> 64-cap; R0/R3: arg=2 -> 128-cap; R4's Afr pushed
// demand to ~200 against the 128 cap -> inner-loop spill, +5.6MB scratch).
// arg=1 -> 256 cap; demand ~200 fits; occupancy unchanged (1 block/CU by
// grid anyway, 2 waves/SIMD, 200x2=400 <= 2048 pool).
// ---------------------------------------------------------------------------
__global__ __launch_bounds__(512, 1) void dcn_main(
        const float* __restrict__ x, const float* __restrict__ off,
        const float* __restrict__ msk, const __bf16* __restrict__ wp,
        const __bf16* __restrict__ xs, const float* __restrict__ bias,
        float* __restrict__ out) {
    __shared__ __align__(16) char smem[SMEM_SZ];  // Bs | Xs; epilogue: f32 scratch
    char* BsB = smem;
    const char* XsB = (const char*)smem + XS_OFF;

    const int tid  = threadIdx.x;
    const int wv   = tid >> 6;
    const int lane = tid & 63;
    const int q    = lane >> 4, rr = lane & 15;
    const int px   = lane;                 // sampling pixel column

    const int bid = blockIdx.x;
    const int xcd = bid & 7;
    const int b   = xcd >> 1;
    const int h   = ((xcd & 1) << 5) | (bid >> 3);

    const int rowbase = min(max(h - 5, 0), HH - NROWS);
    const float* xb = x + (size_t)b * 256 * HW;
    const char* xsb = (const char*)xs;

    // ---- DMA strip assignment: 24 strips (12 rows x 2 sg), 3 per wave -----
    size_t SB[3]; int XD[3];
    #pragma unroll
    for (int k = 0; k < 3; ++k) {
        int t = wv * 3 + k;
        int row = t >> 1, sgh = t & 1;
        SB[k] = (size_t)(b * 64 + rowbase + row) * 32768 + (size_t)(sgh * 1024 + lane * 16);
        XD[k] = XS_OFF + row * 2048 + sgh * 1024;
    }

    // ---- per-thread gather-unit params, computed ONCE ---------------------
    // unit c (0..17): k=0 -> c=wv; k=1 -> c=wv+8; k=2 -> c=wv+10 (waves 6,7).
    float W00[3], W01[3], W10[3], W11[3];
    int AY0[3], AY1[3], DXO[3], COLB[3], GP[3];
    bool UV[3];
    #pragma unroll
    for (int k = 0; k < 3; ++k) {
        int c = (k < 2) ? (wv + 8 * k) : ((wv >= 6) ? wv + 10 : -1);
        UV[k] = (c >= 0);
        if (UV[k]) {
            int sg = c / 9, tap = c % 9;
            int ki = tap / 3, kj = tap - 3 * ki;
            const float* offp = off + (size_t)b * 18 * HW + h * 64 + px;
            float dy = offp[(2 * tap) * HW];
            float dx = offp[(2 * tap + 1) * HW];
            float mv = msk[(size_t)b * 9 * HW + (size_t)tap * HW + h * 64 + px];
            float py  = (float)(h - 1 + ki) + dy;
            float pxf = (float)(px - 1 + kj) + dx;
            float y0f = floorf(py), x0f = floorf(pxf);
            float ly = py - y0f, lx = pxf - x0f;
            float hy = 1.0f - ly, hx = 1.0f - lx;
            int y0 = (int)y0f, x0 = (int)x0f;
            int y1 = y0 + 1, x1 = x0 + 1;
            bool vy0 = (y0 >= 0) && (y0 < HH), vy1 = (y1 >= 0) && (y1 < HH);
            bool vx0 = (x0 >= 0) && (x0 < WW), vx1 = (x1 >= 0) && (x1 < WW);
            int cy0 = min(max(y0, 0), HH - 1), cy1 = min(max(y1, 0), HH - 1);
            int cx0 = min(max(x0, 0), WW - 1), cx1 = min(max(x1, 0), WW - 1);
            W00[k] = (vy0 && vx0) ? hy * hx * mv : 0.0f;
            W01[k] = (vy0 && vx1) ? hy * lx * mv : 0.0f;
            W10[k] = (vy1 && vx0) ? ly * hx * mv : 0.0f;
            W11[k] = (vy1 && vx1) ? ly * lx * mv : 0.0f;
            int ry0 = min(max(cy0 - rowbase, 0), NROWS - 1);
            int ry1 = min(max(cy1 - rowbase, 0), NROWS - 1);
            bool useG = (vy0 && (cy0 < rowbase || cy0 > rowbase + NROWS - 1))
                     || (vy1 && (cy1 < rowbase || cy1 > rowbase + NROWS - 1));
            AY0[k]  = ry0 * 2048 + sg * 1024 + cx0 * 16;
            AY1[k]  = ry1 * 2048 + sg * 1024 + cx0 * 16;
            DXO[k]  = (cx1 - cx0) * 16;
            COLB[k] = (tap * 32 + sg * 8) * 2;
            GP[k]   = cy0 | (cy1 << 6) | (cx0 << 12) | (cx1 << 18) | (sg << 24)
                    | (useG ? (1u << 31) : 0);
        }
    }

    f32x4 acc[4][4];
    #pragma unroll
    for (int i = 0; i < 4; ++i)
        #pragma unroll
        for (int n = 0; n < 4; ++n)
            acc[i][n] = (f32x4)0.0f;

    const int tm0   = (wv & 3) * 4;
    const int klbeg = (wv & 4) ? 5 : 0;
    const int nkl   = (wv & 4) ? 4 : 5;

    bf16x8 Afr[5][4];   // cg A-block, loaded at even stage, used at odd stage

    // ---- prologue: DMA stage 0 --------------------------------------------
    #pragma unroll
    for (int k = 0; k < 3; ++k)
        __builtin_amdgcn_global_load_lds(
            (const __attribute__((address_space(1))) void*)(xsb + SB[k]),
            (__attribute__((address_space(3))) void*)(smem + XD[k]), 16, 0, 0);

    #pragma unroll 1
    for (int s = 0; s < 16; ++s) {
        const int cg = s >> 1, half = s & 1;
        bar_sync_vm();   // Xs(s) landed block-wide; Bs(cg-1) MFMA reads done
        // ---- even stage: issue the WHOLE cg A-block prefetch --------------
        if (!half) {
            const __bf16* ap = wp + ((size_t)((cg * 9 + klbeg) * 16 + tm0) * 64 + lane) * 8;
            #pragma unroll
            for (int t = 0; t < 5; ++t) {
                if (t < nkl) {
                    #pragma unroll
                    for (int i = 0; i < 4; ++i)
                        Afr[t][i] = *(const bf16x8*)(ap + t * 8192 + i * 512);
                }
            }
        }
        // ---- gather: <=3 (c,px) units per thread --------------------------
        #pragma unroll
        for (int k = 0; k < 3; ++k) {
            if (UV[k]) {
                bf16x8 c00 = *(const bf16x8*)(XsB + AY0[k]);
                bf16x8 c01 = *(const bf16x8*)(XsB + AY0[k] + DXO[k]);
                bf16x8 c10 = *(const bf16x8*)(XsB + AY1[k]);
                bf16x8 c11 = *(const bf16x8*)(XsB + AY1[k] + DXO[k]);
                float w0 = W00[k], w1 = W01[k], w2 = W10[k], w3 = W11[k];
                bf16x8 res;
                #pragma unroll
                for (int j = 0; j < 8; ++j) {
                    float v = w0 * (float)c00[j] + w1 * (float)c01[j]
                            + w2 * (float)c10[j] + w3 * (float)c11[j];
                    res[j] = (__bf16)v;
                }
                int gp = GP[k];
                if (gp < 0) {   // rare: valid corner outside staged rows
                    int cy0 = gp & 63, cy1 = (gp >> 6) & 63;
                    int cx0 = (gp >> 12) & 63, cx1 = (gp >> 18) & 63;
                    int sg = (gp >> 24) & 3;
                    const float* xc = xb + (size_t)(cg * 32 + half * 16 + sg * 8) * HW;
                    int i00 = cy0 * 64 + cx0, i01 = cy0 * 64 + cx1;
                    int i10 = cy1 * 64 + cx0, i11 = cy1 * 64 + cx1;
                    #pragma unroll
                    for (int j = 0; j < 8; ++j) {
                        float v = w0 * xc[i00] + w1 * xc[i01]
                                + w2 * xc[i10] + w3 * xc[i11];
                        res[j] = (__bf16)v;
                        xc += HW;
                    }
                }
                *(bf16x8*)(BsB + px * 592 + COLB[k] + half * 32) = res;
            }
        }
        bar_sync();   // Xs reads + Bs(half) writes done block-wide
        // ---- issue next stage's DMA (flies across MFMA + next barrier) ----
        if (s < 15) {
            #pragma unroll
            for (int k = 0; k < 3; ++k)
                __builtin_amdgcn_global_load_lds(
                    (const __attribute__((address_space(1))) void*)(xsb + SB[k] + (size_t)(s + 1) * 2048),
                    (__attribute__((address_space(3))) void*)(smem + XD[k]), 16, 0, 0);
        }
        if (half) {
            // ---- MFMA: register A (prefetched), LDS B; fully unrolled -----
            const char* bp0 = BsB + rr * 592 + (klbeg * 32 + q * 8) * 2;
            #pragma unroll
            for (int t = 0; t < 5; ++t) {
                if (t < nkl) {
                    const char* bp = bp0 + t * 64;
                    bf16x8 bb0 = *(const bf16x8*)(bp);
                    bf16x8 bb1 = *(const bf16x8*)(bp + 16 * 592);
                    bf16x8 bb2 = *(const bf16x8*)(bp + 32 * 592);
                    bf16x8 bb3 = *(const bf16x8*)(bp + 48 * 592);
                    acc[0][0] = __builtin_amdgcn_mfma_f32_16x16x32_bf16(Afr[t][0], bb0, acc[0][0], 0, 0, 0);
                    acc[1][0] = __builtin_amdgcn_mfma_f32_16x16x32_bf16(Afr[t][1], bb0, acc[1][0], 0, 0, 0);
                    acc[2][0] = __builtin_amdgcn_mfma_f32_16x16x32_bf16(Afr[t][2], bb0, acc[2][0], 0, 0, 0);
                    acc[3][0] = __builtin_amdgcn_mfma_f32_16x16x32_bf16(Afr[t][3], bb0, acc[3][0], 0, 0, 0);
                    acc[0][1] = __builtin_amdgcn_mfma_f32_16x16x32_bf16(Afr[t][0], bb1, acc[0][1], 0, 0, 0);
                    acc[1][1] = __builtin_amdgcn_mfma_f32_16x16x32_bf16(Afr[t][1], bb1, acc[1][1], 0, 0, 0);
                    acc[2][1] = __builtin_amdgcn_mfma_f32_16x16x32_bf16(Afr[t][2], bb1, acc[2][1], 0, 0, 0);
                    acc[3][1] = __builtin_amdgcn_mfma_f32_16x16x32_bf16(Afr[t][3], bb1, acc[3][1], 0, 0, 0);
                    acc[0][2] = __builtin_amdgcn_mfma_f32_16x16x32_bf16(Afr[t][0], bb2, acc[0][2], 0, 0, 0);
                    acc[1][2] = __builtin_amdgcn_mfma_f32_16x16x32_bf16(Afr[t][1], bb2, acc[1][2], 0, 0, 0);
                    acc[2][2] = __builtin_amdgcn_mfma_f32_16x16x32_bf16(Afr[t][2], bb2, acc[2][2], 0, 0, 0);
                    acc[3][2] = __builtin_amdgcn_mfma_f32_16x16x32_bf16(Afr[t][3], bb2, acc[3][2], 0, 0, 0);
                    acc[0][3] = __builtin_amdgcn_mfma_f32_16x16x32_bf16(Afr[t][0], bb3, acc[0][3], 0, 0, 0);
                    acc[1][3] = __builtin_amdgcn_mfma_f32_16x16x32_bf16(Afr[t][1], bb3, acc[1][3], 0, 0, 0);
                    acc[2][3] = __builtin_amdgcn_mfma_f32_16x16x32_bf16(Afr[t][2], bb3, acc[2][3], 0, 0, 0);
                    acc[3][3] = __builtin_amdgcn_mfma_f32_16x16x32_bf16(Afr[t][3], bb3, acc[3][3], 0, 0, 0);
                }
            }
        }
    }

    // ---- epilogue: cross-wave kl-partial reduce via LDS, then store -------
    float* scr = (float*)smem;   // Bs/Xs dead now
    bar_sync();
    if (wv >= 4) {
        const int base = (wv - 4) * 4096 + lane * 4;
        #pragma unroll
        for (int i = 0; i < 4; ++i)
            #pragma unroll
            for (int n = 0; n < 4; ++n)
                *(f32x4*)&scr[base + (i * 4 + n) * 256] = acc[i][n];
    }
    bar_sync();
    if (wv < 4) {
        const int mrow = wv * 64;
        const int base = wv * 4096 + lane * 4;
        #pragma unroll
        for (int i = 0; i < 4; ++i) {
            #pragma unroll
            for (int n = 0; n < 4; ++n) {
                f32x4 p = *(const f32x4*)&scr[base + (i * 4 + n) * 256];
                #pragma unroll
                for (int e = 0; e < 4; ++e) {
                    int m = mrow + i * 16 + q * 4 + e;
                    out[((size_t)b * COUT + m) * HW + h * 64 + n * 16 + rr]
                        = acc[i][n][e] + p[e] + bias[m];
                }
            }
        }
    }
}

extern "C" void kernel_launch(void* const* d_in, const int* in_sizes, int n_in,
                              void* d_out, int out_size, void* d_ws, size_t ws_size,
                              hipStream_t stream) {
    const float* x      = (const float*)d_in[0];   // [4,256,64,64]
    const float* off    = (const float*)d_in[1];   // [4,18,64,64]
    const float* msk    = (const float*)d_in[2];   // [4,9,64,64]
    const float* weight = (const float*)d_in[3];   // [256,256,3,3]
    const float* bias   = (const float*)d_in[4];   // [256]
    float* out = (float*)d_out;                    // [4,256,64,64]

    __bf16* wp = (__bf16*)d_ws;                              // 1.18 MB
    __bf16* xs = (__bf16*)((char*)d_ws + 1179648);           // 8 MB transposed x

    prep<<<512, 256, 0, stream>>>(weight, x, wp, xs);
    dcn_main<<<256, 512, 0, stream>>>(x, off, msk, wp, xs, bias, out);
}

// Round 6
// 127.626 us; speedup vs baseline: 1.2725x; 1.2725x over previous
//
#include <hip/hip_runtime.h>

typedef __bf16 bf16x8 __attribute__((ext_vector_type(8)));
typedef float f32x4 __attribute__((ext_vector_type(4)));

#define HH 64
#define WW 64
#define HW 4096
#define COUT 256
#define NROWS 12       // staged input rows [rowbase, rowbase+11]
#define BS_SZ 37888    // one Bs buffer: 64 px rows x 592 B
#define XS_OFF 75776   // Xs after 2x Bs
#define XS_SZ 24576    // one Xs buffer: 12 rows x 2 sg x 64 col x 16 B
#define SMEM_SZ 124928 // Bs0 | Bs1 | Xs0 | Xs1  (<= 160 KB/CU on gfx950)

// lgkm-only barrier: staging DMA stays in flight across it.
__device__ __forceinline__ void bar_sync() {
    asm volatile("s_waitcnt lgkmcnt(0)" ::: "memory");
    __builtin_amdgcn_s_barrier();
    asm volatile("" ::: "memory");
}
// full barrier: drains this wave's global_load_lds DMA before the barrier.
__device__ __forceinline__ void bar_sync_vm() {
    asm volatile("s_waitcnt vmcnt(0) lgkmcnt(0)" ::: "memory");
    __builtin_amdgcn_s_barrier();
    asm volatile("" ::: "memory");
}

// ---------------------------------------------------------------------------
// Kernel 1 (merged pre-pass, 512 blocks):
//   blocks 0..255   : transpose x -> bf16 stage-major xs[b][h][g16][sg][w][c8]
//   blocks 256..511 : blend circle weights -> bf16 pre-fragmented MFMA A.
// ---------------------------------------------------------------------------
__global__ __launch_bounds__(256) void prep(const float* __restrict__ weight,
                                            const float* __restrict__ x,
                                            __bf16* __restrict__ wp,
                                            __bf16* __restrict__ xs) {
    __shared__ float ws[2304];
    const int tid = threadIdx.x;
    if (blockIdx.x < 256) {
        const int bh = blockIdx.x;
        const int b = bh >> 6, h = bh & 63;
        const float* xr = x + (size_t)b * 256 * HW + h * 64;
        #pragma unroll
        for (int it = 0; it < 8; ++it) {
            const int u = it * 256 + tid;        // 16B chunk index 0..2047
            const int gsg = u >> 6, w = u & 63;  // c = gsg*8 + c8
            bf16x8 v;
            #pragma unroll
            for (int c8 = 0; c8 < 8; ++c8)
                v[c8] = (__bf16)xr[(size_t)(gsg * 8 + c8) * HW + w];
            *(bf16x8*)&xs[(size_t)bh * 16384 + (size_t)u * 8] = v;
        }
        return;
    }
    const int o = blockIdx.x - 256;
    const float4* src = (const float4*)(weight + (size_t)o * 2304);
    float4* dst = (float4*)ws;
    #pragma unroll
    for (int i = 0; i < 3; ++i) {
        int idx = i * 256 + tid;
        if (idx < 576) dst[idx] = src[idx];
    }
    __syncthreads();
    const float Af = 0.70710678118654752f;
    const float Bf = 1.0f - Af;
    const int tm = o >> 4, rr = o & 15;
    for (int fid = tid; fid < 288; fid += 256) {
        const int cgtap = fid >> 2, q = fid & 3;
        const int cg = cgtap / 9, tap = cgtap - 9 * cg;
        const int c0 = cg * 32 + q * 8;
        bf16x8 v;
        #pragma unroll
        for (int j = 0; j < 8; ++j) {
            const float* w = ws + (c0 + j) * 9;
            float r;
            switch (tap) {
                case 0:  r = Af*(Af*w[0]+Bf*w[1]) + Bf*(Af*w[3]+Bf*w[4]); break;
                case 1:  r = w[1]; break;
                case 2:  r = Af*(Bf*w[1]+Af*w[2]) + Bf*(Bf*w[4]+Af*w[5]); break;
                case 3:  r = w[3]; break;
                case 4:  r = w[4]; break;
                case 5:  r = w[5]; break;
                case 6:  r = Bf*(Af*w[3]+Bf*w[4]) + Af*(Af*w[6]+Bf*w[7]); break;
                case 7:  r = w[7]; break;
                default: r = Bf*(Bf*w[4]+Af*w[5]) + Af*(Bf*w[7]+Af*w[8]); break;
            }
            v[j] = (__bf16)r;
        }
        *(bf16x8*)&wp[(size_t)(((cg * 9 + tap) * 16 + tm) * 64 + q * 16 + rr) << 3] = v;
    }
}

// ---- MFMA half-part: t in [tb,te) of k-group pcg, rolling A-prefetch ------
__device__ __forceinline__ void mfma_part(const __bf16* __restrict__ wp,
        const char* BsR, int klbeg, int tb, int te, int tm0, int lane,
        int q, int rr, int pcg, f32x4 acc[4][4]) {
    const __bf16* ap = wp + ((size_t)((pcg * 9 + klbeg + tb) * 16 + tm0) * 64 + lane) * 8;
    bf16x8 a0 = *(const bf16x8*)ap;
    bf16x8 a1 = *(const bf16x8*)(ap + 512);
    bf16x8 a2 = *(const bf16x8*)(ap + 1024);
    bf16x8 a3 = *(const bf16x8*)(ap + 1536);
    int kc = ((klbeg + tb) * 32 + q * 8) * 2;
    #pragma unroll 1
    for (int t = tb; t < te; ++t) {
        bf16x8 n0 = a0, n1 = a1, n2 = a2, n3 = a3;
        if (t + 1 < te) {
            const __bf16* np = ap + 8192;
            n0 = *(const bf16x8*)np;
            n1 = *(const bf16x8*)(np + 512);
            n2 = *(const bf16x8*)(np + 1024);
            n3 = *(const bf16x8*)(np + 1536);
        }
        const char* bp = BsR + rr * 592 + kc;
        bf16x8 bb0 = *(const bf16x8*)(bp);
        bf16x8 bb1 = *(const bf16x8*)(bp + 16 * 592);
        bf16x8 bb2 = *(const bf16x8*)(bp + 32 * 592);
        bf16x8 bb3 = *(const bf16x8*)(bp + 48 * 592);
        acc[0][0] = __builtin_amdgcn_mfma_f32_16x16x32_bf16(a0, bb0, acc[0][0], 0, 0, 0);
        acc[1][0] = __builtin_amdgcn_mfma_f32_16x16x32_bf16(a1, bb0, acc[1][0], 0, 0, 0);
        acc[2][0] = __builtin_amdgcn_mfma_f32_16x16x32_bf16(a2, bb0, acc[2][0], 0, 0, 0);
        acc[3][0] = __builtin_amdgcn_mfma_f32_16x16x32_bf16(a3, bb0, acc[3][0], 0, 0, 0);
        acc[0][1] = __builtin_amdgcn_mfma_f32_16x16x32_bf16(a0, bb1, acc[0][1], 0, 0, 0);
        acc[1][1] = __builtin_amdgcn_mfma_f32_16x16x32_bf16(a1, bb1, acc[1][1], 0, 0, 0);
        acc[2][1] = __builtin_amdgcn_mfma_f32_16x16x32_bf16(a2, bb1, acc[2][1], 0, 0, 0);
        acc[3][1] = __builtin_amdgcn_mfma_f32_16x16x32_bf16(a3, bb1, acc[3][1], 0, 0, 0);
        acc[0][2] = __builtin_amdgcn_mfma_f32_16x16x32_bf16(a0, bb2, acc[0][2], 0, 0, 0);
        acc[1][2] = __builtin_amdgcn_mfma_f32_16x16x32_bf16(a1, bb2, acc[1][2], 0, 0, 0);
        acc[2][2] = __builtin_amdgcn_mfma_f32_16x16x32_bf16(a2, bb2, acc[2][2], 0, 0, 0);
        acc[3][2] = __builtin_amdgcn_mfma_f32_16x16x32_bf16(a3, bb2, acc[3][2], 0, 0, 0);
        acc[0][3] = __builtin_amdgcn_mfma_f32_16x16x32_bf16(a0, bb3, acc[0][3], 0, 0, 0);
        acc[1][3] = __builtin_amdgcn_mfma_f32_16x16x32_bf16(a1, bb3, acc[1][3], 0, 0, 0);
        acc[2][3] = __builtin_amdgcn_mfma_f32_16x16x32_bf16(a2, bb3, acc[2][3], 0, 0, 0);
        acc[3][3] = __builtin_amdgcn_mfma_f32_16x16x32_bf16(a3, bb3, acc[3][3], 0, 0, 0);
        ap += 8192;
        kc += 64;
        a0 = n0; a1 = n1; a2 = n2; a3 = n3;
    }
}

// ---------------------------------------------------------------------------
// Kernel 2: DMA-staged bilinear-sample + implicit GEMM, FULLY double-buffered
// (Bs x2, Xs x2) -> ONE barrier per stage; each inter-barrier region holds
// {DMA issue, gather, MFMA half-part} so VALU gather overlaps MFMA via wave
// drift and DMA latency is always covered by a whole region of work (R3's
// structure exposed DMA latency on even stages and serialized gather|MFMA
// into separate barrier segments). Registers stay at R3's ~116 (rolling
// 1-ahead A-prefetch only — the 128-VGPR cap for 512-thr blocks is hard,
// R4/R5 evidence).
// ---------------------------------------------------------------------------
__global__ __launch_bounds__(512, 2) void dcn_main(
        const float* __restrict__ x, const float* __restrict__ off,
        const float* __restrict__ msk, const __bf16* __restrict__ wp,
        const __bf16* __restrict__ xs, const float* __restrict__ bias,
        float* __restrict__ out) {
    __shared__ __align__(16) char smem[SMEM_SZ];  // Bs0|Bs1|Xs0|Xs1; epi: f32 scratch
    const int tid  = threadIdx.x;
    const int wv   = tid >> 6;
    const int lane = tid & 63;
    const int q    = lane >> 4, rr = lane & 15;
    const int px   = lane;                 // sampling pixel column

    const int bid = blockIdx.x;
    const int xcd = bid & 7;
    const int b   = xcd >> 1;
    const int h   = ((xcd & 1) << 5) | (bid >> 3);

    const int rowbase = min(max(h - 5, 0), HH - NROWS);
    const float* xb = x + (size_t)b * 256 * HW;
    const char* xsb = (const char*)xs;

    // ---- DMA strip assignment: 24 strips (12 rows x 2 sg), 3 per wave -----
    size_t SB[3]; int XDR[3];
    #pragma unroll
    for (int k = 0; k < 3; ++k) {
        int t = wv * 3 + k;
        int row = t >> 1, sgh = t & 1;
        SB[k]  = (size_t)(b * 64 + rowbase + row) * 32768 + (size_t)(sgh * 1024 + lane * 16);
        XDR[k] = row * 2048 + sgh * 1024;   // offset within one Xs buffer
    }

    // ---- per-thread gather-unit params, computed ONCE ---------------------
    // unit c (0..17): k=0 -> c=wv; k=1 -> c=wv+8; k=2 -> c=wv+10 (waves 6,7).
    float W00[3], W01[3], W10[3], W11[3];
    int AY0[3], AY1[3], DXO[3], COLB[3], GP[3];
    bool UV[3];
    #pragma unroll
    for (int k = 0; k < 3; ++k) {
        int c = (k < 2) ? (wv + 8 * k) : ((wv >= 6) ? wv + 10 : -1);
        UV[k] = (c >= 0);
        if (UV[k]) {
            int sg = c / 9, tap = c % 9;
            int ki = tap / 3, kj = tap - 3 * ki;
            const float* offp = off + (size_t)b * 18 * HW + h * 64 + px;
            float dy = offp[(2 * tap) * HW];
            float dx = offp[(2 * tap + 1) * HW];
            float mv = msk[(size_t)b * 9 * HW + (size_t)tap * HW + h * 64 + px];
            float py  = (float)(h - 1 + ki) + dy;
            float pxf = (float)(px - 1 + kj) + dx;
            float y0f = floorf(py), x0f = floorf(pxf);
            float ly = py - y0f, lx = pxf - x0f;
            float hy = 1.0f - ly, hx = 1.0f - lx;
            int y0 = (int)y0f, x0 = (int)x0f;
            int y1 = y0 + 1, x1 = x0 + 1;
            bool vy0 = (y0 >= 0) && (y0 < HH), vy1 = (y1 >= 0) && (y1 < HH);
            bool vx0 = (x0 >= 0) && (x0 < WW), vx1 = (x1 >= 0) && (x1 < WW);
            int cy0 = min(max(y0, 0), HH - 1), cy1 = min(max(y1, 0), HH - 1);
            int cx0 = min(max(x0, 0), WW - 1), cx1 = min(max(x1, 0), WW - 1);
            W00[k] = (vy0 && vx0) ? hy * hx * mv : 0.0f;
            W01[k] = (vy0 && vx1) ? hy * lx * mv : 0.0f;
            W10[k] = (vy1 && vx0) ? ly * hx * mv : 0.0f;
            W11[k] = (vy1 && vx1) ? ly * lx * mv : 0.0f;
            int ry0 = min(max(cy0 - rowbase, 0), NROWS - 1);
            int ry1 = min(max(cy1 - rowbase, 0), NROWS - 1);
            bool useG = (vy0 && (cy0 < rowbase || cy0 > rowbase + NROWS - 1))
                     || (vy1 && (cy1 < rowbase || cy1 > rowbase + NROWS - 1));
            AY0[k]  = ry0 * 2048 + sg * 1024 + cx0 * 16;
            AY1[k]  = ry1 * 2048 + sg * 1024 + cx0 * 16;
            DXO[k]  = (cx1 - cx0) * 16;
            COLB[k] = (tap * 32 + sg * 8) * 2;
            GP[k]   = cy0 | (cy1 << 6) | (cx0 << 12) | (cx1 << 18) | (sg << 24)
                    | (useG ? (1u << 31) : 0);
        }
    }

    f32x4 acc[4][4];
    #pragma unroll
    for (int i = 0; i < 4; ++i)
        #pragma unroll
        for (int n = 0; n < 4; ++n)
            acc[i][n] = (f32x4)0.0f;

    const int tm0   = (wv & 3) * 4;
    const int klbeg = (wv & 4) ? 5 : 0;
    const int nkl   = (wv & 4) ? 4 : 5;
    const int thalf = (nkl + 1) >> 1;   // part0 = [0,thalf), part1 = [thalf,nkl)

    // ---- prologue: DMA stage 0 -> Xs[0] -----------------------------------
    #pragma unroll
    for (int k = 0; k < 3; ++k)
        __builtin_amdgcn_global_load_lds(
            (const __attribute__((address_space(1))) void*)(xsb + SB[k]),
            (__attribute__((address_space(3))) void*)(smem + XS_OFF + XDR[k]), 16, 0, 0);

    #pragma unroll 1
    for (int s = 0; s < 16; ++s) {
        const int cg = s >> 1, half = s & 1;
        bar_sync_vm();   // Xs[s&1] landed block-wide; Bs[cg&1] MFMA reads (cg-2)
                         // done; Bs[(cg-1)&1] gather writes (s-1) visible
        // ---- issue next stage's DMA into the OTHER Xs buffer --------------
        if (s < 15) {
            const int xoff = XS_OFF + ((s + 1) & 1) * XS_SZ;
            #pragma unroll
            for (int k = 0; k < 3; ++k)
                __builtin_amdgcn_global_load_lds(
                    (const __attribute__((address_space(1))) void*)(xsb + SB[k] + (size_t)(s + 1) * 2048),
                    (__attribute__((address_space(3))) void*)(smem + xoff + XDR[k]), 16, 0, 0);
        }
        // ---- gather: Xs[s&1] -> Bs[cg&1], <=3 (c,px) units per thread -----
        {
            const char* XsB = (const char*)smem + XS_OFF + (s & 1) * XS_SZ;
            char* BsW = smem + (cg & 1) * BS_SZ;
            #pragma unroll
            for (int k = 0; k < 3; ++k) {
                if (UV[k]) {
                    bf16x8 c00 = *(const bf16x8*)(XsB + AY0[k]);
                    bf16x8 c01 = *(const bf16x8*)(XsB + AY0[k] + DXO[k]);
                    bf16x8 c10 = *(const bf16x8*)(XsB + AY1[k]);
                    bf16x8 c11 = *(const bf16x8*)(XsB + AY1[k] + DXO[k]);
                    float w0 = W00[k], w1 = W01[k], w2 = W10[k], w3 = W11[k];
                    bf16x8 res;
                    #pragma unroll
                    for (int j = 0; j < 8; ++j) {
                        float v = w0 * (float)c00[j] + w1 * (float)c01[j]
                                + w2 * (float)c10[j] + w3 * (float)c11[j];
                        res[j] = (__bf16)v;
                    }
                    int gp = GP[k];
                    if (gp < 0) {   // rare: valid corner outside staged rows
                        int cy0 = gp & 63, cy1 = (gp >> 6) & 63;
                        int cx0 = (gp >> 12) & 63, cx1 = (gp >> 18) & 63;
                        int sg = (gp >> 24) & 3;
                        const float* xc = xb + (size_t)(cg * 32 + half * 16 + sg * 8) * HW;
                        int i00 = cy0 * 64 + cx0, i01 = cy0 * 64 + cx1;
                        int i10 = cy1 * 64 + cx0, i11 = cy1 * 64 + cx1;
                        #pragma unroll
                        for (int j = 0; j < 8; ++j) {
                            float v = w0 * xc[i00] + w1 * xc[i01]
                                    + w2 * xc[i10] + w3 * xc[i11];
                            res[j] = (__bf16)v;
                            xc += HW;
                        }
                    }
                    *(bf16x8*)(BsW + px * 592 + COLB[k] + half * 32) = res;
                }
            }
        }
        // ---- MFMA half-part of previous cg (overlaps gather via drift) ----
        if (s >= 2) {
            const int pcg = cg - 1;
            const char* BsR = (const char*)smem + (pcg & 1) * BS_SZ;
            const int tb = half ? thalf : 0;
            const int te = half ? nkl : thalf;
            mfma_part(wp, BsR, klbeg, tb, te, tm0, lane, q, rr, pcg, acc);
        }
    }

    // ---- tail: cg7 full MFMA ----------------------------------------------
    bar_sync();   // Bs[1] writes (s=15) visible
    mfma_part(wp, (const char*)smem + BS_SZ, klbeg, 0, nkl, tm0, lane, q, rr, 7, acc);

    // ---- epilogue: cross-wave kl-partial reduce via LDS, then store -------
    float* scr = (float*)smem;   // Bs/Xs dead now
    bar_sync();
    if (wv >= 4) {
        const int base = (wv - 4) * 4096 + lane * 4;
        #pragma unroll
        for (int i = 0; i < 4; ++i)
            #pragma unroll
            for (int n = 0; n < 4; ++n)
                *(f32x4*)&scr[base + (i * 4 + n) * 256] = acc[i][n];
    }
    bar_sync();
    if (wv < 4) {
        const int mrow = wv * 64;
        const int base = wv * 4096 + lane * 4;
        #pragma unroll
        for (int i = 0; i < 4; ++i) {
            #pragma unroll
            for (int n = 0; n < 4; ++n) {
                f32x4 p = *(const f32x4*)&scr[base + (i * 4 + n) * 256];
                #pragma unroll
                for (int e = 0; e < 4; ++e) {
                    int m = mrow + i * 16 + q * 4 + e;
                    out[((size_t)b * COUT + m) * HW + h * 64 + n * 16 + rr]
                        = acc[i][n][e] + p[e] + bias[m];
                }
            }
        }
    }
}

extern "C" void kernel_launch(void* const* d_in, const int* in_sizes, int n_in,
                              void* d_out, int out_size, void* d_ws, size_t ws_size,
                              hipStream_t stream) {
    const float* x      = (const float*)d_in[0];   // [4,256,64,64]
    const float* off    = (const float*)d_in[1];   // [4,18,64,64]
    const float* msk    = (const float*)d_in[2];   // [4,9,64,64]
    const float* weight = (const float*)d_in[3];   // [256,256,3,3]
    const float* bias   = (const float*)d_in[4];   // [256]
    float* out = (float*)d_out;                    // [4,256,64,64]

    __bf16* wp = (__bf16*)d_ws;                              // 1.18 MB
    __bf16* xs = (__bf16*)((char*)d_ws + 1179648);           // 8 MB transposed x

    prep<<<512, 256, 0, stream>>>(weight, x, wp, xs);
    dcn_main<<<256, 512, 0, stream>>>(x, off, msk, wp, xs, bias, out);
}